// Round 3
// baseline (1806.349 us; speedup 1.0000x reference)
//
#include <hip/hip_runtime.h>

#define H  512
#define NN 10000
#define SS 20
#define VV 100000
#define EE 100000

typedef __bf16 bf16x8 __attribute__((ext_vector_type(8)));
typedef float  f32x4  __attribute__((ext_vector_type(4)));

__device__ __forceinline__ unsigned short f2bf(float f) {
  unsigned u = __builtin_bit_cast(unsigned, f);
  u += 0x7FFFu + ((u >> 16) & 1u);          // round-to-nearest-even
  return (unsigned short)(u >> 16);
}
__device__ __forceinline__ float bflo(int x) {
  return __builtin_bit_cast(float, (unsigned)x << 16);
}
__device__ __forceinline__ float bfhi(int x) {
  return __builtin_bit_cast(float, (unsigned)x & 0xFFFF0000u);
}
__device__ __forceinline__ float sigm(float x) { return 1.f / (1.f + __expf(-x)); }

__device__ __forceinline__ void cvt_store8(unsigned short* dst, float4 a, float4 b) {
  int4 v;
  v.x = (int)f2bf(a.x) | ((int)f2bf(a.y) << 16);
  v.y = (int)f2bf(a.z) | ((int)f2bf(a.w) << 16);
  v.z = (int)f2bf(b.x) | ((int)f2bf(b.y) << 16);
  v.w = (int)f2bf(b.z) | ((int)f2bf(b.w) << 16);
  *(int4*)dst = v;   // call sites guarantee 16B alignment
}

// ---------------- fused gather + GEMM + GRU scan ----------------------------
// grid: (16 channel-groups of 32, 2500 node-groups of 4). block 256 = 4 waves.
// rows = 4 nodes x 20 steps = 80 = 5 M-tiles; cols = 4 panels x 32 ch = 128.
// hn output: bf16 at hnb[node*1024 + c] (first 1024B of each 2048B out2 slot).
__launch_bounds__(256, 3)
__global__ void gru_fused(const float* __restrict__ emb,
                          const float* __restrict__ W_ir,
                          const float* __restrict__ W_iz,
                          const float* __restrict__ b_ir,
                          const float* __restrict__ b_iz,
                          const int* __restrict__ walk_idx,
                          unsigned short* __restrict__ hnb) {
  __shared__ union {
    struct { unsigned short As[80][72]; unsigned short Bs[128][72]; } ab; // +8 pad
    float Hs[80][128];                                                    // scan buffer
  } sm;
  __shared__ int rowidx[80];

  const int tid = threadIdx.x;
  const int c0 = blockIdx.x * 32;
  const int n0 = blockIdx.y * 4;

  if (tid < 80) {
    int ri = walk_idx[n0 * SS + tid];
    ri = (unsigned)ri < VV ? ri : 0;      // defensive clamp
    rowidx[tid] = ri;
  }

  const int lane = tid & 63;
  const int wv = tid >> 6;
  const int r = lane & 15;
  const int q = lane >> 4;

  const f32x4 fzero = {0.f, 0.f, 0.f, 0.f};
  f32x4 acc[5][2];
  #pragma unroll
  for (int mt = 0; mt < 5; ++mt)
    #pragma unroll
    for (int i = 0; i < 2; ++i) acc[mt][i] = fzero;

  const int kk = (tid & 7) * 8;   // 8 threads per row/col, 8 k-elems each
  const int g8 = tid >> 3;        // 0..31

  for (int k0 = 0; k0 < H; k0 += 64) {
    __syncthreads();
    // ---- A tile: 80 rows x 64 k (gathered emb rows, f32 -> bf16) ----
    #pragma unroll
    for (int it = 0; it < 3; ++it) {
      int row = it * 32 + g8;
      if (row < 80) {
        long off = (long)rowidx[row] * H + k0 + kk;
        float4 a = *(const float4*)(emb + off);
        float4 b = *(const float4*)(emb + off + 4);
        cvt_store8(&sm.ab.As[row][kk], a, b);
      }
    }
    // ---- B tile: 128 cols; col j: panel p=j>>5 (r0,z0,r1,z1), ch c0+(j&31) --
    #pragma unroll
    for (int it = 0; it < 4; ++it) {
      int j = it * 32 + g8;
      int p = j >> 5;
      int c = c0 + (j & 31);
      const float* src = ((p & 1) ? W_iz : W_ir)
                       + ((long)(p >> 1) * H * H + (long)c * H + k0 + kk);
      float4 a = *(const float4*)src;
      float4 b = *(const float4*)(src + 4);
      cvt_store8(&sm.ab.Bs[j][kk], a, b);
    }
    __syncthreads();
    // ---- MFMA: wave wv owns col-tiles {2wv, 2wv+1}, all 5 row-tiles ----
    #pragma unroll
    for (int ks = 0; ks < 2; ++ks) {
      const int kb = ks * 32 + q * 8;
      bf16x8 a[5], b[2];
      #pragma unroll
      for (int mt = 0; mt < 5; ++mt) a[mt] = *(const bf16x8*)&sm.ab.As[mt * 16 + r][kb];
      #pragma unroll
      for (int i = 0; i < 2; ++i) b[i] = *(const bf16x8*)&sm.ab.Bs[(wv * 2 + i) * 16 + r][kb];
      #pragma unroll
      for (int mt = 0; mt < 5; ++mt)
        #pragma unroll
        for (int i = 0; i < 2; ++i)
          acc[mt][i] = __builtin_amdgcn_mfma_f32_16x16x32_bf16(a[mt], b[i], acc[mt][i], 0, 0, 0);
    }
  }
  __syncthreads();
  // ---- dump C (layout: col=lane&15, row=q*4+reg) into scan buffer ----
  #pragma unroll
  for (int mt = 0; mt < 5; ++mt)
    #pragma unroll
    for (int i = 0; i < 2; ++i)
      #pragma unroll
      for (int g = 0; g < 4; ++g)
        sm.Hs[mt * 16 + q * 4 + g][(wv * 2 + i) * 16 + r] = acc[mt][i][g];
  __syncthreads();
  // ---- GRU scan: thread = (node, channel) ----
  if (tid < 128) {
    int nd = tid >> 5;
    int cc = tid & 31;
    int c = c0 + cc;
    float bir0 = b_ir[c], biz0 = b_iz[c], bir1 = b_ir[H + c], biz1 = b_iz[H + c];
    float hn = 0.f;
    int rb = nd * SS;
    #pragma unroll
    for (int s = 0; s < SS; ++s) {
      float h = sm.Hs[rb + s][cc] + bir0;
      float z = sigm(sm.Hs[rb + s][32 + cc] + biz0);
      hn = (1.f - z) * hn + z * h;
    }
    #pragma unroll
    for (int s = 0; s < SS; ++s) {
      float h = sm.Hs[rb + s][64 + cc] + bir1;
      float z = sigm(sm.Hs[rb + s][96 + cc] + biz1);
      hn = (1.f - z) * hn + z * h;
    }
    hnb[(long)(n0 + nd) * 1024 + c] = f2bf(hn);
  }
}

// ------- score slot (raw sigmoid) = sigmoid(hn . lin_w + lin_b) -------------
// writes score[node] at float offset 256 of node's 2048B out2 row slot.
__global__ void score_kernel(const unsigned short* __restrict__ hnb,
                             const float* __restrict__ lin_w,
                             const float* __restrict__ lin_b,
                             float* __restrict__ R) {
  int tid = threadIdx.x;
  int wv = tid >> 6, lane = tid & 63;
  int node = blockIdx.x * 4 + wv;
  int k = lane * 8;
  int4 hv = *(const int4*)(hnb + (long)node * 1024 + k);
  float4 w0 = *(const float4*)(lin_w + k);
  float4 w1 = *(const float4*)(lin_w + k + 4);
  float s = bflo(hv.x) * w0.x + bfhi(hv.x) * w0.y + bflo(hv.y) * w0.z + bfhi(hv.y) * w0.w
          + bflo(hv.z) * w1.x + bfhi(hv.z) * w1.y + bflo(hv.w) * w1.z + bfhi(hv.w) * w1.w;
  #pragma unroll
  for (int off = 32; off > 0; off >>= 1) s += __shfl_down(s, off);
  if (lane == 0) R[256 + (long)node * 512] = sigm(s + lin_b[0]);
}

// ---------------- pred[e] = score[src] * score[dst] -------------------------
__global__ void pred_kernel(const int* __restrict__ eli, const float* __restrict__ R,
                            float* __restrict__ out) {
  int e = blockIdx.x * 256 + threadIdx.x;
  if (e < EE) {
    int a = eli[e];       a = (unsigned)a < NN ? a : 0;   // defensive clamp
    int b = eli[EE + e];  b = (unsigned)b < NN ? b : 0;
    out[e] = R[256 + (long)a * 512] * R[256 + (long)b * 512];
  }
}

// ---------------- out2 = hn @ skip_w.T + skip_b (in-place-safe MFMA) --------
// Block owns 16 rows exclusively: stages its rows' hn bf16 into LDS first,
// then computes all 512 cols and overwrites the same 16 row slots.
__launch_bounds__(256)
__global__ void out2_kernel(const unsigned short* __restrict__ hnb,
                            const float* __restrict__ skip_w,
                            const float* __restrict__ skip_b,
                            float* __restrict__ out2) {
  __shared__ unsigned short As[16][520];   // +8 pad: row stride 1040B (16B-aligned)
  __shared__ unsigned short Bs[512][40];   // 32 k-chunk + 8 pad
  const int tid = threadIdx.x;
  const int lane = tid & 63, wv = tid >> 6;
  const int r = lane & 15, q = lane >> 4;
  const int m0 = blockIdx.x * 16;

  // stage A: 16 rows x 512 k bf16 (each thread: 32 contiguous shorts)
  {
    int arow = tid >> 4;
    int acol = (tid & 15) * 32;
    const unsigned short* hr = hnb + (long)(m0 + arow) * 1024 + acol;
    *(int4*)&As[arow][acol]      = *(const int4*)(hr);
    *(int4*)&As[arow][acol + 8]  = *(const int4*)(hr + 8);
    *(int4*)&As[arow][acol + 16] = *(const int4*)(hr + 16);
    *(int4*)&As[arow][acol + 24] = *(const int4*)(hr + 24);
  }

  const f32x4 fzero = {0.f, 0.f, 0.f, 0.f};
  f32x4 acc[8];
  #pragma unroll
  for (int i = 0; i < 8; ++i) acc[i] = fzero;

  const int ksub = (tid & 3) * 8;
  const int jb = tid >> 2;                 // 0..63

  for (int k0 = 0; k0 < H; k0 += 32) {
    __syncthreads();                       // orders A-stage + prev MFMA reads
    #pragma unroll
    for (int it = 0; it < 8; ++it) {
      int j = it * 64 + jb;
      const float* src = skip_w + (long)j * H + k0 + ksub;
      cvt_store8(&Bs[j][ksub], *(const float4*)src, *(const float4*)(src + 4));
    }
    __syncthreads();
    bf16x8 af = *(const bf16x8*)&As[r][k0 + q * 8];
    #pragma unroll
    for (int i = 0; i < 8; ++i) {
      bf16x8 bf = *(const bf16x8*)&Bs[(wv * 8 + i) * 16 + r][q * 8];
      acc[i] = __builtin_amdgcn_mfma_f32_16x16x32_bf16(af, bf, acc[i], 0, 0, 0);
    }
  }
  // C layout: row(M) = q*4+g, col-in-tile(N) = r
  #pragma unroll
  for (int i = 0; i < 8; ++i) {
    int col = (wv * 8 + i) * 16 + r;
    float sb = skip_b[col];
    #pragma unroll
    for (int g = 0; g < 4; ++g)
      out2[(long)(m0 + q * 4 + g) * H + col] = acc[i][g] + sb;
  }
}

// ---------------- host launcher (d_ws intentionally unused) -----------------
extern "C" void kernel_launch(void* const* d_in, const int* in_sizes, int n_in,
                              void* d_out, int out_size, void* d_ws, size_t ws_size,
                              hipStream_t stream) {
  const float* emb    = (const float*)d_in[0];
  const float* W_ir   = (const float*)d_in[1];
  const float* b_ir   = (const float*)d_in[2];
  const float* W_iz   = (const float*)d_in[3];
  const float* b_iz   = (const float*)d_in[4];
  const float* lin_w  = (const float*)d_in[5];
  const float* lin_b  = (const float*)d_in[6];
  const float* skip_w = (const float*)d_in[7];
  const float* skip_b = (const float*)d_in[8];
  const int*   walk   = (const int*)d_in[9];
  const int*   eli    = (const int*)d_in[10];
  float* out = (float*)d_out;
  float* R   = out + EE;                           // out2 region: NN x H f32
  unsigned short* hnb = (unsigned short*)R;        // bf16 hn inside out2 slots

  dim3 g1(16, 2500);
  gru_fused<<<g1, 256, 0, stream>>>(emb, W_ir, W_iz, b_ir, b_iz, walk, hnb);
  score_kernel<<<2500, 256, 0, stream>>>(hnb, lin_w, lin_b, R);
  pred_kernel<<<391, 256, 0, stream>>>(eli, R, out);        // before out2 (slots reused)
  out2_kernel<<<625, 256, 0, stream>>>(hnb, skip_w, skip_b, R);
}

// Round 4
// 1759.670 us; speedup vs baseline: 1.0265x; 1.0265x over previous
//
#include <hip/hip_runtime.h>

#define H  512
#define NN 10000
#define SS 20
#define VV 100000
#define EE 100000

typedef __bf16 bf16x8 __attribute__((ext_vector_type(8)));
typedef float  f32x4  __attribute__((ext_vector_type(4)));

__device__ __forceinline__ unsigned short f2bf(float f) {
  unsigned u = __builtin_bit_cast(unsigned, f);
  u += 0x7FFFu + ((u >> 16) & 1u);          // round-to-nearest-even
  return (unsigned short)(u >> 16);
}
__device__ __forceinline__ float bflo(int x) {
  return __builtin_bit_cast(float, (unsigned)x << 16);
}
__device__ __forceinline__ float bfhi(int x) {
  return __builtin_bit_cast(float, (unsigned)x & 0xFFFF0000u);
}
__device__ __forceinline__ float sigm(float x) { return 1.f / (1.f + __expf(-x)); }

__device__ __forceinline__ void cvt_store8(unsigned short* dst, float4 a, float4 b) {
  int4 v;
  v.x = (int)f2bf(a.x) | ((int)f2bf(a.y) << 16);
  v.y = (int)f2bf(a.z) | ((int)f2bf(a.w) << 16);
  v.z = (int)f2bf(b.x) | ((int)f2bf(b.y) << 16);
  v.w = (int)f2bf(b.z) | ((int)f2bf(b.w) << 16);
  *(int4*)dst = v;   // call sites guarantee 16B alignment
}

// XOR-swizzled tile addressing: row stride = 64 shorts = 8 granules of 16B.
// physical short index of (row, granule g) = row*64 + (g ^ (row&7))*8.
// Every 8-consecutive-lane octet hits all 8 bank groups in both the staging
// writes (lane octet = fixed row, g=0..7) and fragment reads (fixed g,
// r=8 consecutive) -> conflict-free b128 LDS ops.  [round-4 fix: the old
// +8-short pad gave (row+g) mod 8 aliasing = 8-way conflicts = 4.4e8 cycles]
__device__ __forceinline__ int swz(int row, int g) {
  return row * 64 + ((g ^ (row & 7)) * 8);
}

// ---------------- fused gather + GEMM + GRU scan ----------------------------
// grid: (16 channel-groups of 32, 2500 node-groups of 4). block 256 = 4 waves.
// rows = 4 nodes x 20 steps = 80 = 5 M-tiles; cols = 4 panels x 32 ch = 128.
// hn output: bf16 at hnb[node*1024 + c] (first 1024B of each 2048B out2 slot).
__launch_bounds__(256, 3)
__global__ void gru_fused(const float* __restrict__ emb,
                          const float* __restrict__ W_ir,
                          const float* __restrict__ W_iz,
                          const float* __restrict__ b_ir,
                          const float* __restrict__ b_iz,
                          const int* __restrict__ walk_idx,
                          unsigned short* __restrict__ hnb) {
  __shared__ union {
    struct { unsigned short A[80 * 64]; unsigned short B[128 * 64]; } ab; // 26624 B
    float Hs[80][132];   // scan buffer (reuse); stride 132: 2-way max banks
  } sm;
  __shared__ int rowoff[80];   // element offset of each gathered emb row

  const int tid = threadIdx.x;
  const int c0 = blockIdx.x * 32;
  const int n0 = blockIdx.y * 4;

  if (tid < 80) {
    int ri = walk_idx[n0 * SS + tid];
    ri = (unsigned)ri < VV ? ri : 0;      // defensive clamp
    rowoff[tid] = ri * H;
  }

  const int lane = tid & 63;
  const int wv = tid >> 6;
  const int r = lane & 15;
  const int q = lane >> 4;

  const f32x4 fzero = {0.f, 0.f, 0.f, 0.f};
  f32x4 acc[5][2];
  #pragma unroll
  for (int mt = 0; mt < 5; ++mt)
    #pragma unroll
    for (int i = 0; i < 2; ++i) acc[mt][i] = fzero;

  const int k8 = tid & 7;         // granule (8 shorts = 16B) within row
  const int g8 = tid >> 3;        // 0..31

  for (int k0 = 0; k0 < H; k0 += 64) {
    __syncthreads();
    // ---- A tile: 80 rows x 64 k (gathered emb rows, f32 -> bf16) ----
    #pragma unroll
    for (int it = 0; it < 3; ++it) {
      int row = it * 32 + g8;
      if (row < 80) {
        long off = (long)rowoff[row] + k0 + k8 * 8;
        float4 a = *(const float4*)(emb + off);
        float4 b = *(const float4*)(emb + off + 4);
        cvt_store8(&sm.ab.A[swz(row, k8)], a, b);
      }
    }
    // ---- B tile: 128 cols; col j: panel p=j>>5 (r0,z0,r1,z1), ch c0+(j&31) --
    #pragma unroll
    for (int it = 0; it < 4; ++it) {
      int j = it * 32 + g8;
      int p = j >> 5;
      int c = c0 + (j & 31);
      const float* src = ((p & 1) ? W_iz : W_ir)
                       + ((long)(p >> 1) * H * H + (long)c * H + k0 + k8 * 8);
      float4 a = *(const float4*)src;
      float4 b = *(const float4*)(src + 4);
      cvt_store8(&sm.ab.B[swz(j, k8)], a, b);
    }
    __syncthreads();
    // ---- MFMA: wave wv owns col-tiles {2wv, 2wv+1}, all 5 row-tiles ----
    #pragma unroll
    for (int ks = 0; ks < 2; ++ks) {
      const int g = ks * 4 + q;   // k-granule of this lane's fragment
      bf16x8 a[5], b[2];
      #pragma unroll
      for (int mt = 0; mt < 5; ++mt)
        a[mt] = *(const bf16x8*)&sm.ab.A[swz(mt * 16 + r, g)];
      #pragma unroll
      for (int i = 0; i < 2; ++i)
        b[i] = *(const bf16x8*)&sm.ab.B[swz((wv * 2 + i) * 16 + r, g)];
      #pragma unroll
      for (int mt = 0; mt < 5; ++mt)
        #pragma unroll
        for (int i = 0; i < 2; ++i)
          acc[mt][i] = __builtin_amdgcn_mfma_f32_16x16x32_bf16(a[mt], b[i], acc[mt][i], 0, 0, 0);
    }
  }
  __syncthreads();
  // ---- dump C (layout: col=lane&15, row=q*4+reg) into scan buffer ----
  #pragma unroll
  for (int mt = 0; mt < 5; ++mt)
    #pragma unroll
    for (int i = 0; i < 2; ++i)
      #pragma unroll
      for (int g = 0; g < 4; ++g)
        sm.Hs[mt * 16 + q * 4 + g][(wv * 2 + i) * 16 + r] = acc[mt][i][g];
  __syncthreads();
  // ---- GRU scan: thread = (node, channel) ----
  if (tid < 128) {
    int nd = tid >> 5;
    int cc = tid & 31;
    int c = c0 + cc;
    float bir0 = b_ir[c], biz0 = b_iz[c], bir1 = b_ir[H + c], biz1 = b_iz[H + c];
    float hn = 0.f;
    int rb = nd * SS;
    #pragma unroll
    for (int s = 0; s < SS; ++s) {
      float h = sm.Hs[rb + s][cc] + bir0;
      float z = sigm(sm.Hs[rb + s][32 + cc] + biz0);
      hn = (1.f - z) * hn + z * h;
    }
    #pragma unroll
    for (int s = 0; s < SS; ++s) {
      float h = sm.Hs[rb + s][64 + cc] + bir1;
      float z = sigm(sm.Hs[rb + s][96 + cc] + biz1);
      hn = (1.f - z) * hn + z * h;
    }
    hnb[(long)(n0 + nd) * 1024 + c] = f2bf(hn);
  }
}

// ------- score slot (raw sigmoid) = sigmoid(hn . lin_w + lin_b) -------------
// writes score[node] at float offset 256 of node's 2048B out2 row slot.
__global__ void score_kernel(const unsigned short* __restrict__ hnb,
                             const float* __restrict__ lin_w,
                             const float* __restrict__ lin_b,
                             float* __restrict__ R) {
  int tid = threadIdx.x;
  int wv = tid >> 6, lane = tid & 63;
  int node = blockIdx.x * 4 + wv;
  int k = lane * 8;
  int4 hv = *(const int4*)(hnb + (long)node * 1024 + k);
  float4 w0 = *(const float4*)(lin_w + k);
  float4 w1 = *(const float4*)(lin_w + k + 4);
  float s = bflo(hv.x) * w0.x + bfhi(hv.x) * w0.y + bflo(hv.y) * w0.z + bfhi(hv.y) * w0.w
          + bflo(hv.z) * w1.x + bfhi(hv.z) * w1.y + bflo(hv.w) * w1.z + bfhi(hv.w) * w1.w;
  #pragma unroll
  for (int off = 32; off > 0; off >>= 1) s += __shfl_down(s, off);
  if (lane == 0) R[256 + (long)node * 512] = sigm(s + lin_b[0]);
}

// ---------------- pred[e] = score[src] * score[dst] -------------------------
__global__ void pred_kernel(const int* __restrict__ eli, const float* __restrict__ R,
                            float* __restrict__ out) {
  int e = blockIdx.x * 256 + threadIdx.x;
  if (e < EE) {
    int a = eli[e];       a = (unsigned)a < NN ? a : 0;   // defensive clamp
    int b = eli[EE + e];  b = (unsigned)b < NN ? b : 0;
    out[e] = R[256 + (long)a * 512] * R[256 + (long)b * 512];
  }
}

// ---------------- out2 = hn @ skip_w.T + skip_b (in-place-safe MFMA) --------
// Block owns 16 rows exclusively: stages its rows' hn bf16 into LDS first,
// then computes all 512 cols and overwrites the same 16 row slots.
__launch_bounds__(256)
__global__ void out2_kernel(const unsigned short* __restrict__ hnb,
                            const float* __restrict__ skip_w,
                            const float* __restrict__ skip_b,
                            float* __restrict__ out2) {
  __shared__ unsigned short As[16][520];   // +8 pad: row stride 1040B (16B-aligned)
  __shared__ unsigned short Bs[512][40];   // 32 k-chunk + 8 pad
  const int tid = threadIdx.x;
  const int lane = tid & 63, wv = tid >> 6;
  const int r = lane & 15, q = lane >> 4;
  const int m0 = blockIdx.x * 16;

  // stage A: 16 rows x 512 k bf16 (each thread: 32 contiguous shorts)
  {
    int arow = tid >> 4;
    int acol = (tid & 15) * 32;
    const unsigned short* hr = hnb + (long)(m0 + arow) * 1024 + acol;
    *(int4*)&As[arow][acol]      = *(const int4*)(hr);
    *(int4*)&As[arow][acol + 8]  = *(const int4*)(hr + 8);
    *(int4*)&As[arow][acol + 16] = *(const int4*)(hr + 16);
    *(int4*)&As[arow][acol + 24] = *(const int4*)(hr + 24);
  }

  const f32x4 fzero = {0.f, 0.f, 0.f, 0.f};
  f32x4 acc[8];
  #pragma unroll
  for (int i = 0; i < 8; ++i) acc[i] = fzero;

  const int ksub = (tid & 3) * 8;
  const int jb = tid >> 2;                 // 0..63

  for (int k0 = 0; k0 < H; k0 += 32) {
    __syncthreads();                       // orders A-stage + prev MFMA reads
    #pragma unroll
    for (int it = 0; it < 8; ++it) {
      int j = it * 64 + jb;
      const float* src = skip_w + (long)j * H + k0 + ksub;
      cvt_store8(&Bs[j][ksub], *(const float4*)src, *(const float4*)(src + 4));
    }
    __syncthreads();
    bf16x8 af = *(const bf16x8*)&As[r][k0 + q * 8];
    #pragma unroll
    for (int i = 0; i < 8; ++i) {
      bf16x8 bf = *(const bf16x8*)&Bs[(wv * 8 + i) * 16 + r][q * 8];
      acc[i] = __builtin_amdgcn_mfma_f32_16x16x32_bf16(af, bf, acc[i], 0, 0, 0);
    }
  }
  // C layout: row(M) = q*4+g, col-in-tile(N) = r
  #pragma unroll
  for (int i = 0; i < 8; ++i) {
    int col = (wv * 8 + i) * 16 + r;
    float sb = skip_b[col];
    #pragma unroll
    for (int g = 0; g < 4; ++g)
      out2[(long)(m0 + q * 4 + g) * H + col] = acc[i][g] + sb;
  }
}

// ---------------- host launcher (d_ws intentionally unused) -----------------
extern "C" void kernel_launch(void* const* d_in, const int* in_sizes, int n_in,
                              void* d_out, int out_size, void* d_ws, size_t ws_size,
                              hipStream_t stream) {
  const float* emb    = (const float*)d_in[0];
  const float* W_ir   = (const float*)d_in[1];
  const float* b_ir   = (const float*)d_in[2];
  const float* W_iz   = (const float*)d_in[3];
  const float* b_iz   = (const float*)d_in[4];
  const float* lin_w  = (const float*)d_in[5];
  const float* lin_b  = (const float*)d_in[6];
  const float* skip_w = (const float*)d_in[7];
  const float* skip_b = (const float*)d_in[8];
  const int*   walk   = (const int*)d_in[9];
  const int*   eli    = (const int*)d_in[10];
  float* out = (float*)d_out;
  float* R   = out + EE;                           // out2 region: NN x H f32
  unsigned short* hnb = (unsigned short*)R;        // bf16 hn inside out2 slots

  dim3 g1(16, 2500);
  gru_fused<<<g1, 256, 0, stream>>>(emb, W_ir, W_iz, b_ir, b_iz, walk, hnb);
  score_kernel<<<2500, 256, 0, stream>>>(hnb, lin_w, lin_b, R);
  pred_kernel<<<391, 256, 0, stream>>>(eli, R, out);        // before out2 (slots reused)
  out2_kernel<<<625, 256, 0, stream>>>(hnb, skip_w, skip_b, R);
}

// Round 5
// 1058.580 us; speedup vs baseline: 1.7064x; 1.6623x over previous
//
#include <hip/hip_runtime.h>

#define H  512
#define NN 10000
#define SS 20
#define VV 100000
#define EE 100000

typedef __bf16 bf16x8 __attribute__((ext_vector_type(8)));
typedef float  f32x4  __attribute__((ext_vector_type(4)));

__device__ __forceinline__ unsigned short f2bf(float f) {
  unsigned u = __builtin_bit_cast(unsigned, f);
  u += 0x7FFFu + ((u >> 16) & 1u);          // round-to-nearest-even
  return (unsigned short)(u >> 16);
}
__device__ __forceinline__ float bflo(int x) {
  return __builtin_bit_cast(float, (unsigned)x << 16);
}
__device__ __forceinline__ float bfhi(int x) {
  return __builtin_bit_cast(float, (unsigned)x & 0xFFFF0000u);
}
__device__ __forceinline__ float sigm(float x) { return 1.f / (1.f + __expf(-x)); }

__device__ __forceinline__ void cvt_store8(unsigned short* dst, float4 a, float4 b) {
  int4 v;
  v.x = (int)f2bf(a.x) | ((int)f2bf(a.y) << 16);
  v.y = (int)f2bf(a.z) | ((int)f2bf(a.w) << 16);
  v.z = (int)f2bf(b.x) | ((int)f2bf(b.y) << 16);
  v.w = (int)f2bf(b.z) | ((int)f2bf(b.w) << 16);
  *(int4*)dst = v;
}
__device__ __forceinline__ bf16x8 cvt8(float4 a, float4 b) {
  int4 v;
  v.x = (int)f2bf(a.x) | ((int)f2bf(a.y) << 16);
  v.y = (int)f2bf(a.z) | ((int)f2bf(a.w) << 16);
  v.z = (int)f2bf(b.x) | ((int)f2bf(b.y) << 16);
  v.w = (int)f2bf(b.z) | ((int)f2bf(b.w) << 16);
  return __builtin_bit_cast(bf16x8, v);
}

// ---------------- fused gather + GEMM + GRU scan (persistent-B) -------------
// grid (16 cgroups, 32 node-splits), block 512 = 8 waves.
// Wave w owns cols j=16w..16w+15; col j = (channel c0+(j>>2), panel j&3).
// B-fragments (full K=512) live in 64 VGPRs per lane, converted ONCE.
// Block loops ~78 node-groups (4 nodes = 80 rows = 5 M-tiles), staging only
// the A chunk (80x64k bf16, 2 LDS buffers, depth-1 register prefetch).
// A rows are PERMUTED: LDS row m=16mt+4q+g holds logical (node q, step 4mt+g),
// so each lane's acc regs hold 20 consecutive steps of one node -> lane-local
// GRU scan with shfl_xor(1) for h/z pairing; layer-2 via affine composition.
__launch_bounds__(512, 2)
__global__ void gru_fused(const float* __restrict__ emb,
                          const float* __restrict__ W_ir,
                          const float* __restrict__ W_iz,
                          const float* __restrict__ b_ir,
                          const float* __restrict__ b_iz,
                          const int* __restrict__ walk,
                          unsigned short* __restrict__ hnb) {
  __shared__ unsigned short As[2][80 * 64];   // 2 x 10 KB

  const int tid = threadIdx.x;
  const int w = tid >> 6, lane = tid & 63;
  const int r = lane & 15, q = lane >> 4;
  const int c0 = blockIdx.x * 32;

  // ---- persistent B fragments: 16 k-steps x 8 bf16 = 64 VGPRs ----
  const int j = 16 * w + r;
  const int pp = j & 3;                       // panel: 0=r0,1=z0,2=r1,3=z1
  const int cch = c0 + (j >> 2);
  const float* wrow = ((pp & 1) ? W_iz : W_ir)
                    + (long)(pp >> 1) * H * H + (long)cch * H;
  bf16x8 barr[16];
  #pragma unroll
  for (int t = 0; t < 16; ++t) {
    const float* s = wrow + (4 * t + q) * 8;  // k = t*32 + q*8 (matches frag layout)
    barr[t] = cvt8(*(const float4*)s, *(const float4*)(s + 4));
  }
  const float bias = (pp == 0) ? b_ir[cch] : (pp == 1) ? b_iz[cch]
                   : (pp == 2) ? b_ir[H + cch] : b_iz[H + cch];

  // ---- A staging role: thread -> (row, granule); rows 64-79 by tid<128 ----
  const int row0 = tid >> 3, g0 = tid & 7;
  const int row1 = 64 + (tid >> 3);
  const int L0 = 20 * ((row0 >> 2) & 3) + 4 * (row0 >> 4) + (row0 & 3);
  const int L1 = 20 * ((row1 >> 2) & 3) + 4 * (row1 >> 4) + (row1 & 3);
  const int sw0 = row0 * 64 + ((g0 ^ (row0 & 7)) * 8);   // XOR-swizzled dest
  const int sw1 = row1 * 64 + ((g0 ^ (row1 & 7)) * 8);
  const bool two = (tid < 128);

  const int sb = blockIdx.y;
  const int ngA = (2500 * sb) >> 5;
  const int ngB = (2500 * (sb + 1)) >> 5;

  int v0 = walk[ngA * 80 + L0]; v0 = ((unsigned)v0 < VV) ? v0 : 0;
  int cur0 = v0 * H;
  int cur1 = 0;
  if (two) { int v1 = walk[ngA * 80 + L1]; v1 = ((unsigned)v1 < VV) ? v1 : 0; cur1 = v1 * H; }

  float4 pa0 = {0,0,0,0}, pb0 = {0,0,0,0}, pa1 = {0,0,0,0}, pb1 = {0,0,0,0};
  {                                           // prologue: prefetch chunk 0
    const float* s0 = emb + cur0 + g0 * 8;
    pa0 = *(const float4*)s0; pb0 = *(const float4*)(s0 + 4);
    if (two) { const float* s1 = emb + cur1 + g0 * 8;
               pa1 = *(const float4*)s1; pb1 = *(const float4*)(s1 + 4); }
  }

  f32x4 acc[5];
  const f32x4 fz = {0.f, 0.f, 0.f, 0.f};

  for (int ng = ngA; ng < ngB; ++ng) {
    #pragma unroll
    for (int mt = 0; mt < 5; ++mt) acc[mt] = fz;

    const int ngn = (ng + 1 < ngB) ? ng + 1 : ng;   // clamped walk prefetch
    int n0v = walk[ngn * 80 + L0]; n0v = ((unsigned)n0v < VV) ? n0v : 0;
    const int nxt0 = n0v * H;
    int nxt1 = 0;
    if (two) { int n1v = walk[ngn * 80 + L1]; n1v = ((unsigned)n1v < VV) ? n1v : 0; nxt1 = n1v * H; }

    #pragma unroll
    for (int kc = 0; kc < 8; ++kc) {
      unsigned short* Ab = &As[kc & 1][0];
      // consume prefetched chunk kc -> LDS
      cvt_store8(&Ab[sw0], pa0, pb0);
      if (two) cvt_store8(&Ab[sw1], pa1, pb1);
      // issue prefetch for chunk kc+1 (or next ng's chunk 0)
      {
        const int ko = (kc < 7) ? (kc + 1) * 64 : 0;
        const int o0 = (kc < 7) ? cur0 : nxt0;
        const int o1 = (kc < 7) ? cur1 : nxt1;
        const float* s0 = emb + o0 + ko + g0 * 8;
        pa0 = *(const float4*)s0; pb0 = *(const float4*)(s0 + 4);
        if (two) { const float* s1 = emb + o1 + ko + g0 * 8;
                   pa1 = *(const float4*)s1; pb1 = *(const float4*)(s1 + 4); }
      }
      __syncthreads();
      #pragma unroll
      for (int ks = 0; ks < 2; ++ks) {
        const bf16x8 bf = barr[kc * 2 + ks];
        #pragma unroll
        for (int mt = 0; mt < 5; ++mt) {
          const int ar = mt * 16 + r;
          const bf16x8 af =
              *(const bf16x8*)&Ab[ar * 64 + (((ks * 4 + q) ^ (ar & 7)) * 8)];
          acc[mt] = __builtin_amdgcn_mfma_f32_16x16x32_bf16(af, bf, acc[mt], 0, 0, 0);
        }
      }
    }

    // ---- epilogue: lane-local scan; lane (q,r) = node q, col j ----
    // acc[s>>2][s&3] = preact(node q, step s, col j). shfl_xor(1) pairs h/z.
    float hn1 = 0.f, a2 = 1.f, b2 = 0.f;
    #pragma unroll
    for (int s = 0; s < 20; ++s) {
      const float y = acc[s >> 2][s & 3] + bias;
      const float t = __shfl_xor(y, 1);
      const float z = sigm(t);
      hn1 += z * (y - hn1);        // valid on p0 lanes (layer 1 direct scan)
      a2 *= (1.f - z);             // valid on p2 lanes (layer 2 affine)
      b2 += z * (y - b2);
    }
    const float u = __shfl_xor(hn1, 2);       // p2 gets p0's hn1
    if (pp == 2)
      hnb[(long)(ng * 4 + q) * 1024 + cch] = f2bf(a2 * u + b2);

    cur0 = nxt0; cur1 = nxt1;
  }
}

// ------- score slot (raw sigmoid) = sigmoid(hn . lin_w + lin_b) -------------
__global__ void score_kernel(const unsigned short* __restrict__ hnb,
                             const float* __restrict__ lin_w,
                             const float* __restrict__ lin_b,
                             float* __restrict__ R) {
  int tid = threadIdx.x;
  int wv = tid >> 6, lane = tid & 63;
  int node = blockIdx.x * 4 + wv;
  int k = lane * 8;
  int4 hv = *(const int4*)(hnb + (long)node * 1024 + k);
  float4 w0 = *(const float4*)(lin_w + k);
  float4 w1 = *(const float4*)(lin_w + k + 4);
  float s = bflo(hv.x) * w0.x + bfhi(hv.x) * w0.y + bflo(hv.y) * w0.z + bfhi(hv.y) * w0.w
          + bflo(hv.z) * w1.x + bfhi(hv.z) * w1.y + bflo(hv.w) * w1.z + bfhi(hv.w) * w1.w;
  #pragma unroll
  for (int off = 32; off > 0; off >>= 1) s += __shfl_down(s, off);
  if (lane == 0) R[256 + (long)node * 512] = sigm(s + lin_b[0]);
}

// ---------------- pred[e] = score[src] * score[dst] -------------------------
__global__ void pred_kernel(const int* __restrict__ eli, const float* __restrict__ R,
                            float* __restrict__ out) {
  int e = blockIdx.x * 256 + threadIdx.x;
  if (e < EE) {
    int a = eli[e];       a = (unsigned)a < NN ? a : 0;
    int b = eli[EE + e];  b = (unsigned)b < NN ? b : 0;
    out[e] = R[256 + (long)a * 512] * R[256 + (long)b * 512];
  }
}

// ---------------- out2 = hn @ skip_w.T + skip_b (in-place-safe MFMA) --------
__launch_bounds__(256)
__global__ void out2_kernel(const unsigned short* __restrict__ hnb,
                            const float* __restrict__ skip_w,
                            const float* __restrict__ skip_b,
                            float* __restrict__ out2) {
  __shared__ unsigned short Asl[16][520];
  __shared__ unsigned short Bsl[512][40];
  const int tid = threadIdx.x;
  const int lane = tid & 63, wv = tid >> 6;
  const int r = lane & 15, q = lane >> 4;
  const int m0 = blockIdx.x * 16;

  {
    int arow = tid >> 4;
    int acol = (tid & 15) * 32;
    const unsigned short* hr = hnb + (long)(m0 + arow) * 1024 + acol;
    *(int4*)&Asl[arow][acol]      = *(const int4*)(hr);
    *(int4*)&Asl[arow][acol + 8]  = *(const int4*)(hr + 8);
    *(int4*)&Asl[arow][acol + 16] = *(const int4*)(hr + 16);
    *(int4*)&Asl[arow][acol + 24] = *(const int4*)(hr + 24);
  }

  const f32x4 fzero = {0.f, 0.f, 0.f, 0.f};
  f32x4 acc[8];
  #pragma unroll
  for (int i = 0; i < 8; ++i) acc[i] = fzero;

  const int ksub = (tid & 3) * 8;
  const int jb = tid >> 2;

  for (int k0 = 0; k0 < H; k0 += 32) {
    __syncthreads();
    #pragma unroll
    for (int it = 0; it < 8; ++it) {
      int jj = it * 64 + jb;
      const float* src = skip_w + (long)jj * H + k0 + ksub;
      cvt_store8(&Bsl[jj][ksub], *(const float4*)src, *(const float4*)(src + 4));
    }
    __syncthreads();
    bf16x8 af = *(const bf16x8*)&Asl[r][k0 + q * 8];
    #pragma unroll
    for (int i = 0; i < 8; ++i) {
      bf16x8 bf = *(const bf16x8*)&Bsl[(wv * 8 + i) * 16 + r][q * 8];
      acc[i] = __builtin_amdgcn_mfma_f32_16x16x32_bf16(af, bf, acc[i], 0, 0, 0);
    }
  }
  #pragma unroll
  for (int i = 0; i < 8; ++i) {
    int col = (wv * 8 + i) * 16 + r;
    float sbv = skip_b[col];
    #pragma unroll
    for (int g = 0; g < 4; ++g)
      out2[(long)(m0 + q * 4 + g) * H + col] = acc[i][g] + sbv;
  }
}

// ---------------- host launcher (d_ws intentionally unused) -----------------
extern "C" void kernel_launch(void* const* d_in, const int* in_sizes, int n_in,
                              void* d_out, int out_size, void* d_ws, size_t ws_size,
                              hipStream_t stream) {
  const float* emb    = (const float*)d_in[0];
  const float* W_ir   = (const float*)d_in[1];
  const float* b_ir   = (const float*)d_in[2];
  const float* W_iz   = (const float*)d_in[3];
  const float* b_iz   = (const float*)d_in[4];
  const float* lin_w  = (const float*)d_in[5];
  const float* lin_b  = (const float*)d_in[6];
  const float* skip_w = (const float*)d_in[7];
  const float* skip_b = (const float*)d_in[8];
  const int*   walk   = (const int*)d_in[9];
  const int*   eli    = (const int*)d_in[10];
  float* out = (float*)d_out;
  float* R   = out + EE;                           // out2 region: NN x H f32
  unsigned short* hnb = (unsigned short*)R;        // bf16 hn inside out2 slots

  dim3 g1(16, 32);
  gru_fused<<<g1, 512, 0, stream>>>(emb, W_ir, W_iz, b_ir, b_iz, walk, hnb);
  score_kernel<<<2500, 256, 0, stream>>>(hnb, lin_w, lin_b, R);
  pred_kernel<<<391, 256, 0, stream>>>(eli, R, out);        // before out2 (slots reused)
  out2_kernel<<<625, 256, 0, stream>>>(hnb, skip_w, skip_b, R);
}

// Round 6
// 823.442 us; speedup vs baseline: 2.1937x; 1.2856x over previous
//
#include <hip/hip_runtime.h>

#define H  512
#define NN 10000
#define SS 20
#define VV 100000
#define EE 100000

typedef __bf16 bf16x8 __attribute__((ext_vector_type(8)));
typedef float  f32x4  __attribute__((ext_vector_type(4)));

__device__ __forceinline__ unsigned short f2bf(float f) {
  unsigned u = __builtin_bit_cast(unsigned, f);
  u += 0x7FFFu + ((u >> 16) & 1u);          // round-to-nearest-even
  return (unsigned short)(u >> 16);
}
__device__ __forceinline__ float bflo(int x) {
  return __builtin_bit_cast(float, (unsigned)x << 16);
}
__device__ __forceinline__ float bfhi(int x) {
  return __builtin_bit_cast(float, (unsigned)x & 0xFFFF0000u);
}
__device__ __forceinline__ float sigm(float x) { return 1.f / (1.f + __expf(-x)); }

// pack two f32 -> two bf16 in one dword: round-half-up (+0x8000) then
// v_perm_b32 grabs the two high halves. 3 VALU per 2 elems (vs ~8 for RNE).
__device__ __forceinline__ unsigned pk(float lo, float hi) {
  unsigned a = __builtin_bit_cast(unsigned, lo) + 0x8000u;
  unsigned b = __builtin_bit_cast(unsigned, hi) + 0x8000u;
  return __builtin_amdgcn_perm(b, a, 0x07060302u);   // D={b3,b2,a3,a2}
}
__device__ __forceinline__ void cvt_store8(unsigned short* dst, float4 a, float4 b) {
  int4 v;
  v.x = (int)pk(a.x, a.y); v.y = (int)pk(a.z, a.w);
  v.z = (int)pk(b.x, b.y); v.w = (int)pk(b.z, b.w);
  *(int4*)dst = v;
}
__device__ __forceinline__ bf16x8 cvt8(float4 a, float4 b) {
  int4 v;
  v.x = (int)pk(a.x, a.y); v.y = (int)pk(a.z, a.w);
  v.z = (int)pk(b.x, b.y); v.w = (int)pk(b.z, b.w);
  return __builtin_bit_cast(bf16x8, v);
}

// ---------------- fused gather + GEMM + GRU scan (persistent-B, 2 N-tiles) --
// grid (16 cgroups of 32 ch, 64 node-splits), block 256 = 4 waves.
// Wave w owns 32 cols in 2 N-tiles: tile t col j=32w+16t+r -> panel pp=r&3
// (r0,z0,r1,z1), channel c0+8w+4t+(r>>2). B (full K=512) persists in 128
// VGPRs/lane, converted once -> each A-fragment ds_read feeds 2 MFMAs.
// A rows PERMUTED in LDS: row m=16mt+4q+g holds (node q, step 4mt+g) so the
// GRU scan is lane-local (shfl_xor(1) pairs h/z, shfl_xor(2) layer2 affine).
__launch_bounds__(256, 2)
__global__ void gru_fused(const float* __restrict__ emb,
                          const float* __restrict__ W_ir,
                          const float* __restrict__ W_iz,
                          const float* __restrict__ b_ir,
                          const float* __restrict__ b_iz,
                          const int* __restrict__ walk,
                          unsigned short* __restrict__ hnb) {
  __shared__ unsigned short As[2][80 * 64];   // 2 x 10 KB, XOR-swizzled granules

  const int tid = threadIdx.x;
  const int w = tid >> 6, lane = tid & 63;
  const int r = lane & 15, q = lane >> 4;
  const int c0 = blockIdx.x * 32;

  // ---- persistent B fragments: 2 tiles x 16 k-steps x 8 bf16 = 128 VGPRs ----
  const int pp = r & 3;                       // panel: 0=r0,1=z0,2=r1,3=z1
  const int chbase = c0 + 8 * w + (r >> 2);
  bf16x8 barr[2][16];
  float bias[2];
  #pragma unroll
  for (int t = 0; t < 2; ++t) {
    const int cch = chbase + 4 * t;
    const float* wrow = ((pp & 1) ? W_iz : W_ir)
                      + (long)(pp >> 1) * H * H + (long)cch * H;
    #pragma unroll
    for (int ks = 0; ks < 16; ++ks) {
      const float* s = wrow + ks * 32 + q * 8;
      barr[t][ks] = cvt8(*(const float4*)s, *(const float4*)(s + 4));
    }
    bias[t] = ((pp & 1) ? b_iz : b_ir)[(pp >> 1) * H + cch];
  }

  // ---- A staging roles: thread -> rows {t>>3, +32, +64(if tid<128)} ----
  const int row0 = tid >> 3, g0 = tid & 7;
  const int row1 = row0 + 32, row2 = row0 + 64;
  const bool has2 = (tid < 128);
  #define LMAP(m) (20 * (((m) >> 2) & 3) + 4 * ((m) >> 4) + ((m) & 3))
  #define SWZ(m)  ((m) * 64 + ((g0 ^ ((m) & 7)) * 8))
  const int L0 = LMAP(row0), L1 = LMAP(row1), L2 = LMAP(row2);
  const int sw0 = SWZ(row0), sw1 = SWZ(row1), sw2 = SWZ(row2);

  const int sb = blockIdx.y;
  const int ngA = (2500 * sb) >> 6;
  const int ngB = (2500 * (sb + 1)) >> 6;

  int v0 = walk[ngA * 80 + L0]; v0 = ((unsigned)v0 < VV) ? v0 : 0;
  int v1 = walk[ngA * 80 + L1]; v1 = ((unsigned)v1 < VV) ? v1 : 0;
  int cur0 = v0 * H, cur1 = v1 * H, cur2 = 0;
  if (has2) { int v2 = walk[ngA * 80 + L2]; v2 = ((unsigned)v2 < VV) ? v2 : 0; cur2 = v2 * H; }

  float4 pa0, pb0, pa1, pb1, pa2 = {0,0,0,0}, pb2 = {0,0,0,0};
  {                                           // prologue: prefetch chunk 0
    const float* s0 = emb + cur0 + g0 * 8;
    pa0 = *(const float4*)s0; pb0 = *(const float4*)(s0 + 4);
    const float* s1 = emb + cur1 + g0 * 8;
    pa1 = *(const float4*)s1; pb1 = *(const float4*)(s1 + 4);
    if (has2) { const float* s2 = emb + cur2 + g0 * 8;
                pa2 = *(const float4*)s2; pb2 = *(const float4*)(s2 + 4); }
  }

  f32x4 acc[5][2];
  const f32x4 fz = {0.f, 0.f, 0.f, 0.f};

  for (int ng = ngA; ng < ngB; ++ng) {
    #pragma unroll
    for (int mt = 0; mt < 5; ++mt)
      #pragma unroll
      for (int t = 0; t < 2; ++t) acc[mt][t] = fz;

    const int ngn = (ng + 1 < ngB) ? ng + 1 : ng;   // clamped walk prefetch
    int n0 = walk[ngn * 80 + L0]; n0 = ((unsigned)n0 < VV) ? n0 : 0;
    int n1 = walk[ngn * 80 + L1]; n1 = ((unsigned)n1 < VV) ? n1 : 0;
    const int nxt0 = n0 * H, nxt1 = n1 * H;
    int nxt2 = 0;
    if (has2) { int n2 = walk[ngn * 80 + L2]; n2 = ((unsigned)n2 < VV) ? n2 : 0; nxt2 = n2 * H; }

    #pragma unroll
    for (int kc = 0; kc < 8; ++kc) {
      unsigned short* Ab = &As[kc & 1][0];
      // consume prefetched chunk kc -> LDS
      cvt_store8(&Ab[sw0], pa0, pb0);
      cvt_store8(&Ab[sw1], pa1, pb1);
      if (has2) cvt_store8(&Ab[sw2], pa2, pb2);
      // issue prefetch for chunk kc+1 (or next ng's chunk 0)
      {
        const int ko = (kc < 7) ? (kc + 1) * 64 : 0;
        const int o0 = (kc < 7) ? cur0 : nxt0;
        const int o1 = (kc < 7) ? cur1 : nxt1;
        const int o2 = (kc < 7) ? cur2 : nxt2;
        const float* s0 = emb + o0 + ko + g0 * 8;
        pa0 = *(const float4*)s0; pb0 = *(const float4*)(s0 + 4);
        const float* s1 = emb + o1 + ko + g0 * 8;
        pa1 = *(const float4*)s1; pb1 = *(const float4*)(s1 + 4);
        if (has2) { const float* s2 = emb + o2 + ko + g0 * 8;
                    pa2 = *(const float4*)s2; pb2 = *(const float4*)(s2 + 4); }
      }
      __syncthreads();
      #pragma unroll
      for (int ks = 0; ks < 2; ++ks) {
        bf16x8 a[5];
        #pragma unroll
        for (int mt = 0; mt < 5; ++mt) {
          const int ar = mt * 16 + r;
          a[mt] = *(const bf16x8*)&Ab[ar * 64 + (((ks * 4 + q) ^ (ar & 7)) * 8)];
        }
        #pragma unroll
        for (int mt = 0; mt < 5; ++mt)
          #pragma unroll
          for (int t = 0; t < 2; ++t)
            acc[mt][t] = __builtin_amdgcn_mfma_f32_16x16x32_bf16(
                a[mt], barr[t][kc * 2 + ks], acc[mt][t], 0, 0, 0);
      }
    }

    // ---- epilogue: lane-local scan per N-tile; lane (q,r) = node q ----
    #pragma unroll
    for (int t = 0; t < 2; ++t) {
      float hn1 = 0.f, a2 = 1.f, b2 = 0.f;
      #pragma unroll
      for (int s = 0; s < 20; ++s) {
        const float y = acc[s >> 2][t][s & 3] + bias[t];
        const float tt = __shfl_xor(y, 1);
        const float z = sigm(tt);
        hn1 += z * (y - hn1);        // layer-1 direct scan (valid on p0 lanes)
        a2 *= (1.f - z);             // layer-2 affine (valid on p2 lanes)
        b2 += z * (y - b2);
      }
      const float u = __shfl_xor(hn1, 2);     // p2 gets p0's hn1
      if (pp == 2)
        hnb[(long)(ng * 4 + q) * 1024 + chbase + 4 * t] = f2bf(a2 * u + b2);
    }

    cur0 = nxt0; cur1 = nxt1; cur2 = nxt2;
  }
}

// ------- score slot (raw sigmoid) = sigmoid(hn . lin_w + lin_b) -------------
__global__ void score_kernel(const unsigned short* __restrict__ hnb,
                             const float* __restrict__ lin_w,
                             const float* __restrict__ lin_b,
                             float* __restrict__ R) {
  int tid = threadIdx.x;
  int wv = tid >> 6, lane = tid & 63;
  int node = blockIdx.x * 4 + wv;
  int k = lane * 8;
  int4 hv = *(const int4*)(hnb + (long)node * 1024 + k);
  float4 w0 = *(const float4*)(lin_w + k);
  float4 w1 = *(const float4*)(lin_w + k + 4);
  float s = bflo(hv.x) * w0.x + bfhi(hv.x) * w0.y + bflo(hv.y) * w0.z + bfhi(hv.y) * w0.w
          + bflo(hv.z) * w1.x + bfhi(hv.z) * w1.y + bflo(hv.w) * w1.z + bfhi(hv.w) * w1.w;
  #pragma unroll
  for (int off = 32; off > 0; off >>= 1) s += __shfl_down(s, off);
  if (lane == 0) R[256 + (long)node * 512] = sigm(s + lin_b[0]);
}

// ---------------- pred[e] = score[src] * score[dst] -------------------------
__global__ void pred_kernel(const int* __restrict__ eli, const float* __restrict__ R,
                            float* __restrict__ out) {
  int e = blockIdx.x * 256 + threadIdx.x;
  if (e < EE) {
    int a = eli[e];       a = (unsigned)a < NN ? a : 0;
    int b = eli[EE + e];  b = (unsigned)b < NN ? b : 0;
    out[e] = R[256 + (long)a * 512] * R[256 + (long)b * 512];
  }
}

// ---------------- out2 = hn @ skip_w.T + skip_b (in-place-safe MFMA) --------
__launch_bounds__(256)
__global__ void out2_kernel(const unsigned short* __restrict__ hnb,
                            const float* __restrict__ skip_w,
                            const float* __restrict__ skip_b,
                            float* __restrict__ out2) {
  __shared__ unsigned short Asl[16][520];
  __shared__ unsigned short Bsl[512][40];
  const int tid = threadIdx.x;
  const int lane = tid & 63, wv = tid >> 6;
  const int r = lane & 15, q = lane >> 4;
  const int m0 = blockIdx.x * 16;

  {
    int arow = tid >> 4;
    int acol = (tid & 15) * 32;
    const unsigned short* hr = hnb + (long)(m0 + arow) * 1024 + acol;
    *(int4*)&Asl[arow][acol]      = *(const int4*)(hr);
    *(int4*)&Asl[arow][acol + 8]  = *(const int4*)(hr + 8);
    *(int4*)&Asl[arow][acol + 16] = *(const int4*)(hr + 16);
    *(int4*)&Asl[arow][acol + 24] = *(const int4*)(hr + 24);
  }

  const f32x4 fzero = {0.f, 0.f, 0.f, 0.f};
  f32x4 acc[8];
  #pragma unroll
  for (int i = 0; i < 8; ++i) acc[i] = fzero;

  const int ksub = (tid & 3) * 8;
  const int jb = tid >> 2;

  for (int k0 = 0; k0 < H; k0 += 32) {
    __syncthreads();
    #pragma unroll
    for (int it = 0; it < 8; ++it) {
      int jj = it * 64 + jb;
      const float* src = skip_w + (long)jj * H + k0 + ksub;
      cvt_store8(&Bsl[jj][ksub], *(const float4*)src, *(const float4*)(src + 4));
    }
    __syncthreads();
    bf16x8 af = *(const bf16x8*)&Asl[r][k0 + q * 8];
    #pragma unroll
    for (int i = 0; i < 8; ++i) {
      bf16x8 bf = *(const bf16x8*)&Bsl[(wv * 8 + i) * 16 + r][q * 8];
      acc[i] = __builtin_amdgcn_mfma_f32_16x16x32_bf16(af, bf, acc[i], 0, 0, 0);
    }
  }
  #pragma unroll
  for (int i = 0; i < 8; ++i) {
    int col = (wv * 8 + i) * 16 + r;
    float sbv = skip_b[col];
    #pragma unroll
    for (int g = 0; g < 4; ++g)
      out2[(long)(m0 + q * 4 + g) * H + col] = acc[i][g] + sbv;
  }
}

// ---------------- host launcher (d_ws intentionally unused) -----------------
extern "C" void kernel_launch(void* const* d_in, const int* in_sizes, int n_in,
                              void* d_out, int out_size, void* d_ws, size_t ws_size,
                              hipStream_t stream) {
  const float* emb    = (const float*)d_in[0];
  const float* W_ir   = (const float*)d_in[1];
  const float* b_ir   = (const float*)d_in[2];
  const float* W_iz   = (const float*)d_in[3];
  const float* b_iz   = (const float*)d_in[4];
  const float* lin_w  = (const float*)d_in[5];
  const float* lin_b  = (const float*)d_in[6];
  const float* skip_w = (const float*)d_in[7];
  const float* skip_b = (const float*)d_in[8];
  const int*   walk   = (const int*)d_in[9];
  const int*   eli    = (const int*)d_in[10];
  float* out = (float*)d_out;
  float* R   = out + EE;                           // out2 region: NN x H f32
  unsigned short* hnb = (unsigned short*)R;        // bf16 hn inside out2 slots

  dim3 g1(16, 64);
  gru_fused<<<g1, 256, 0, stream>>>(emb, W_ir, W_iz, b_ir, b_iz, walk, hnb);
  score_kernel<<<2500, 256, 0, stream>>>(hnb, lin_w, lin_b, R);
  pred_kernel<<<391, 256, 0, stream>>>(eli, R, out);        // before out2 (slots reused)
  out2_kernel<<<625, 256, 0, stream>>>(hnb, skip_w, skip_b, R);
}